// Round 6
// baseline (217.387 us; speedup 1.0000x reference)
//
#include <hip/hip_runtime.h>
#include <hip/hip_bf16.h>
#include <cstdint>
#include <cstddef>

// Problem constants (L=256, C=20, LC=5120, BATCH=1024)
#define LCN 5120
#define BN  1024
#define CN  20

typedef __attribute__((ext_vector_type(4))) float  floatx4;
typedef __attribute__((ext_vector_type(8))) short  shortx8;
typedef __attribute__((ext_vector_type(4))) unsigned short ushortx4;
typedef __attribute__((ext_vector_type(8))) unsigned short ushortx8;

static __device__ __forceinline__ unsigned short f2bf(float f) {
    __hip_bfloat16 h = __float2bfloat16(f);
    return *reinterpret_cast<unsigned short*>(&h);
}

static __device__ __forceinline__ void gload_lds16(const void* g, void* l) {
    __builtin_amdgcn_global_load_lds(
        (const __attribute__((address_space(1))) void*)g,
        (__attribute__((address_space(3))) void*)l,
        16, 0, 0);
}

// ---------------------------------------------------------------------------
// Pass 1 (fused prep), symmetric decomposition:
//   quad[b] = sum_i x[b,i] * ( sum_j Theta[i,j] * (l_j > l_i) * x[b,j] )
// B operand = Theta's OWN ROWS (k = j contiguous) — no transpose.
//
//  blocks [0, 1280): masked streaming bf16 convert (4 rows/block, 1 row/wave):
//      Tb[i][j] = bf16(theta[i*5120+j]) if j >= jmin_i else 0
//      jmin_i = 20*(i/20 + 1); stored for j >= js, js = 1024-chunk-aligned
//      start for i's 256-row GEMM n-tile (matches k_quad's c0 formula).
//  blocks [1280, 2304): per batch row b:
//      out[b] = theta_0 + dot(theta_lc, x[b]);  Xb[b,:] = bf16(x[b,:])
// ---------------------------------------------------------------------------
__global__ __launch_bounds__(256) void k_prep(
    const float* __restrict__ th,    // [5120,5120] theta_lclc
    const float* __restrict__ x,     // [1024,5120]
    const float* __restrict__ th0,   // [1]
    const float* __restrict__ thlc,  // [5120]
    unsigned short* __restrict__ Tb, // [5120,5120] bf16 masked theta (row-major)
    unsigned short* __restrict__ Xb, // [1024,5120] bf16 x
    float*          __restrict__ out)
{
    const int tid = threadIdx.x;
    if (blockIdx.x < LCN / 4) {
        // ---- masked streaming convert of theta rows ----
        const int w = tid >> 6, lane = tid & 63;
        const int i = blockIdx.x * 4 + w;                  // row (groups never straddle 256)
        const int lmin = ((i >> 8) << 8) / CN;             // min l in this row's 256-tile
        const int js   = 1024 * ((CN * (lmin + 1)) / 1024);// first chunk-aligned col stored
        const int jmin = CN * (i / CN) + CN;               // mask: valid iff j >= jmin
        const float* src = th + (size_t)i * LCN;
        unsigned short* dst = Tb + (size_t)i * LCN;
        // (5120 - js) is a multiple of 512 -> uniform trip count across lanes
        for (int j = js + lane * 8; j < LCN; j += 512) {
            const floatx4 v0 = *reinterpret_cast<const floatx4*>(src + j);
            const floatx4 v1 = *reinterpret_cast<const floatx4*>(src + j + 4);
            ushortx8 o;
#pragma unroll
            for (int e = 0; e < 4; ++e) o[e]     = (j + e     >= jmin) ? f2bf(v0[e]) : (unsigned short)0;
#pragma unroll
            for (int e = 0; e < 4; ++e) o[4 + e] = (j + 4 + e >= jmin) ? f2bf(v1[e]) : (unsigned short)0;
            *reinterpret_cast<ushortx8*>(dst + j) = o;
        }
    } else {
        // ---- linear term + x -> bf16 ----
        const int b = blockIdx.x - LCN / 4;
        const floatx4* xr = reinterpret_cast<const floatx4*>(x + (size_t)b * LCN);
        const floatx4* tr = reinterpret_cast<const floatx4*>(thlc);
        ushortx4* xw = reinterpret_cast<ushortx4*>(Xb + (size_t)b * LCN);
        float s = 0.0f;
        for (int k = tid; k < LCN / 4; k += 256) {
            const floatx4 a = xr[k], t2 = tr[k];
            s += a[0] * t2[0] + a[1] * t2[1] + a[2] * t2[2] + a[3] * t2[3];
            ushortx4 o;
#pragma unroll
            for (int e = 0; e < 4; ++e) o[e] = f2bf(a[e]);
            xw[k] = o;
        }
#pragma unroll
        for (int off = 32; off > 0; off >>= 1) s += __shfl_down(s, off, 64);
        __shared__ float ws4[4];
        if ((tid & 63) == 0) ws4[tid >> 6] = s;
        __syncthreads();
        if (tid == 0) out[b] = th0[0] + ws4[0] + ws4[1] + ws4[2] + ws4[3];
    }
}

// ---------------------------------------------------------------------------
// Pass 2: masked-GEMM + fused dot-reduce.
// 256x256 tile, BK=64, 8 waves (2M x 4N), K-chunks of 1024 -> 16 PHASES.
// 60 suffix chunks x 4 m-tiles = 240 blocks (grid 256, 16 early-exit);
// m-siblings of a chunk share an XCD (bid%8 RR) -> Tb HBM-fetched once.
//
// 2-buffer / 16-phase schedule, ONE barrier + ONE vmcnt(0) per phase:
//   phase p: vmcnt(0) [stage p landed; issued a full MFMA-phase (~2500cyc)
//   earlier so the wait is pre-satisfied] -> barrier -> issue stage p+1
//   (targets buf (p+1)&1, last read at phase p-1 -> readers provably done
//   at the barrier) -> 24 ds_read_b128 frags -> 64 MFMA.
// Staging addresses HOISTED: 8 global pointers/thread advanced +=64/phase
// (kills the per-step 64-bit row*LCN multiplies that cost 12% VALUBusy).
// LDS SEG SWIZZLE for 8-seg rows: slot = (seg + row) & 7; write side uses
// pre-permuted global seg (constant per thread); read conflicts <=2-way.
// ---------------------------------------------------------------------------
__global__ __launch_bounds__(512, 2) void k_quad(
    const unsigned short* __restrict__ Xb,   // [1024][5120] bf16
    const unsigned short* __restrict__ Tb,   // [5120][5120] bf16 masked theta
    float*                __restrict__ out)  // [1024]
{
    const int bid  = blockIdx.x;
    const int xcd  = bid & 7;
    const int slot = bid >> 3;
    const int m    = slot & 3;    // M tile (256 rows of batch)
    const int cl   = slot >> 2;   // chunk-local index on this XCD
    int qc = cl * 8 + xcd;        // chunk ordinal 0..59
    if (qc >= 60) return;

    // map chunk ordinal -> (n-tile, k-chunk) over 1024-wide suffix chunks
    int n = 0, cs = 0;
    for (int t = 0; t < 20; ++t) {
        const int lmin = (256 * t) / CN;
        const int c0   = (CN * (lmin + 1)) / 1024;
        const int cnt  = 5 - c0;
        if (qc < cnt) { n = t; cs = c0 + qc; break; }
        qc -= cnt;
    }
    const int b0 = m * 256;
    const int n0 = n * 256;
    const int k0 = cs * 1024;

    __shared__ unsigned short As[2 * 256 * 64];   // 2-buf A: [row][8 swizzled 16B segs]
    __shared__ unsigned short Bs[2 * 256 * 64];   // 2-buf B
    __shared__ float partial[256];

    const int tid  = threadIdx.x;
    const int lane = tid & 63;
    const int w    = tid >> 6;        // wave 0..7
    const int wm   = w & 1;           // M half (128 rows)
    const int wn   = w >> 1;          // N quarter (64 cols)
    const int lrow = lane & 15;
    const int kq   = lane >> 4;       // 0..3

    if (tid < 256) partial[tid] = 0.0f;

    floatx4 acc[8][4];
#pragma unroll
    for (int mt = 0; mt < 8; ++mt)
#pragma unroll
        for (int nt = 0; nt < 4; ++nt) acc[mt][nt] = (floatx4)0.0f;

    // ---- staging constants (fixed per thread) ----
    // linear LDS slot S = t*512 + tid (16B units); row = S>>3 = t*64 + (tid>>3);
    // slot-in-row = tid&7; it holds global seg (slot - row) & 7 (constant!).
    const int rbase = tid >> 3;                     // 0..63
    const int gseg  = ((tid & 7) - (rbase & 7)) & 7;
    const unsigned short* aS[4];
    const unsigned short* bS[4];
#pragma unroll
    for (int t = 0; t < 4; ++t) {
        aS[t] = Xb + (size_t)(b0 + t * 64 + rbase) * LCN + k0 + gseg * 8;
        bS[t] = Tb + (size_t)(n0 + t * 64 + rbase) * LCN + k0 + gseg * 8;
    }

    // ---- fragment read offsets (ushort units within one buffer) ----
    // frag (row, ks, kq) lives at slot ((ks*4+kq) + row) & 7 of the row.
    int aoff[8][2], boff[4][2];
#pragma unroll
    for (int mt = 0; mt < 8; ++mt) {
        const int row = wm * 128 + mt * 16 + lrow;
#pragma unroll
        for (int ks = 0; ks < 2; ++ks)
            aoff[mt][ks] = row * 64 + ((((ks << 2) | kq) + row) & 7) * 8;
    }
#pragma unroll
    for (int nt = 0; nt < 4; ++nt) {
        const int row = wn * 64 + nt * 16 + lrow;
#pragma unroll
        for (int ks = 0; ks < 2; ++ks)
            boff[nt][ks] = row * 64 + ((((ks << 2) | kq) + row) & 7) * 8;
    }

    // stage one 256x64 A-tile + B-tile into buffer `cur`; 2048 16B segs each,
    // 512 threads -> 4 segs/thread/array. LDS dest linear (wave-uniform base
    // + lane*16); swizzle via the pre-permuted GLOBAL source seg. Pointers
    // advance to the next phase's K inside the macro.
#define STAGE64(cur) do {                                                         \
    _Pragma("unroll")                                                             \
    for (int t = 0; t < 4; ++t) {                                                 \
        char* la = (char*)As + (cur) * 32768 + (size_t)(t * 512 + w * 64) * 16;   \
        char* lb = (char*)Bs + (cur) * 32768 + (size_t)(t * 512 + w * 64) * 16;   \
        gload_lds16(aS[t], la);                                                   \
        gload_lds16(bS[t], lb);                                                   \
        aS[t] += 64; bS[t] += 64;                                                 \
    }                                                                             \
} while (0)

    STAGE64(0);                                  // prologue: 8 loads in flight

    for (int p = 0; p < 16; ++p) {
        const int cur = p & 1;
        asm volatile("s_waitcnt vmcnt(0)" ::: "memory");  // stage p landed (pre-satisfied)
        __builtin_amdgcn_s_barrier();            // all waves: data ready, prev readers done
        if (p < 15) STAGE64(cur ^ 1);            // issue stage p+1 (buf read at p-1)

        const unsigned short* Ab = As + cur * 16384;
        const unsigned short* Bb = Bs + cur * 16384;
#pragma unroll
        for (int ks = 0; ks < 2; ++ks) {
            shortx8 bf4[4], af8[8];
#pragma unroll
            for (int nt = 0; nt < 4; ++nt)
                bf4[nt] = *reinterpret_cast<const shortx8*>(Bb + boff[nt][ks]);
#pragma unroll
            for (int mt = 0; mt < 8; ++mt)
                af8[mt] = *reinterpret_cast<const shortx8*>(Ab + aoff[mt][ks]);
            __builtin_amdgcn_s_setprio(1);
#pragma unroll
            for (int mt = 0; mt < 8; ++mt)
#pragma unroll
                for (int nt = 0; nt < 4; ++nt)
                    acc[mt][nt] = __builtin_amdgcn_mfma_f32_16x16x32_bf16(af8[mt], bf4[nt], acc[mt][nt], 0, 0, 0);
            __builtin_amdgcn_s_setprio(0);
        }
    }
#undef STAGE64

    // Epilogue: C/D layout col = lane&15 (i), row = (lane>>4)*4 + reg (b)
#pragma unroll
    for (int mt = 0; mt < 8; ++mt) {
#pragma unroll
        for (int r = 0; r < 4; ++r) {
            const int b = b0 + wm * 128 + mt * 16 + kq * 4 + r;
            float s = 0.0f;
#pragma unroll
            for (int nt = 0; nt < 4; ++nt) {
                const int i = n0 + wn * 64 + nt * 16 + lrow;
                const __hip_bfloat16 hv = *reinterpret_cast<const __hip_bfloat16*>(&Xb[(size_t)b * LCN + i]);
                s += acc[mt][nt][r] * __bfloat162float(hv);
            }
            s += __shfl_xor(s, 1, 64);
            s += __shfl_xor(s, 2, 64);
            s += __shfl_xor(s, 4, 64);
            s += __shfl_xor(s, 8, 64);
            if (lrow == 0) atomicAdd(&partial[b - b0], s);
        }
    }
    __syncthreads();
    if (tid < 256) atomicAdd(&out[b0 + tid], partial[tid]);
}

// ---------------------------------------------------------------------------
extern "C" void kernel_launch(void* const* d_in, const int* in_sizes, int n_in,
                              void* d_out, int out_size, void* d_ws, size_t ws_size,
                              hipStream_t stream) {
    const float* x      = (const float*)d_in[0];  // [1024, 5120]
    const float* th0    = (const float*)d_in[1];  // [1]
    const float* thlc   = (const float*)d_in[2];  // [5120]
    const float* thlclc = (const float*)d_in[3];  // [5120, 5120]
    float* out = (float*)d_out;                   // [1024]

    // ws layout: Tb (bf16 5120x5120 = 52.4 MB) | Xb (bf16 1024x5120 = 10.5 MB)
    unsigned short* Tb = (unsigned short*)d_ws;
    unsigned short* Xb = (unsigned short*)((char*)d_ws + (size_t)LCN * LCN * 2);

    // fused prep: 1280 theta-convert blocks + 1024 init blocks
    k_prep<<<dim3(LCN / 4 + BN), 256, 0, stream>>>(thlclc, x, th0, thlc, Tb, Xb, out);

    // 60 chunks x 4 m-tiles, padded to 8 chunk-slots per XCD: 8*8*4 = 256 blocks
    k_quad<<<dim3(256), 512, 0, stream>>>(Xb, Tb, out);
}

// Round 7
// 214.687 us; speedup vs baseline: 1.0126x; 1.0126x over previous
//
#include <hip/hip_runtime.h>
#include <hip/hip_bf16.h>
#include <cstdint>
#include <cstddef>

// Problem constants (L=256, C=20, LC=5120, BATCH=1024)
#define LCN 5120
#define BN  1024
#define CN  20

typedef __attribute__((ext_vector_type(4))) float  floatx4;
typedef __attribute__((ext_vector_type(8))) short  shortx8;
typedef __attribute__((ext_vector_type(4))) unsigned short ushortx4;
typedef __attribute__((ext_vector_type(8))) unsigned short ushortx8;

static __device__ __forceinline__ unsigned short f2bf(float f) {
    __hip_bfloat16 h = __float2bfloat16(f);
    return *reinterpret_cast<unsigned short*>(&h);
}

static __device__ __forceinline__ void gload_lds16(const void* g, void* l) {
    __builtin_amdgcn_global_load_lds(
        (const __attribute__((address_space(1))) void*)g,
        (__attribute__((address_space(3))) void*)l,
        16, 0, 0);
}

// ---------------------------------------------------------------------------
// Pass 1 (fused prep), symmetric decomposition:
//   quad[b] = sum_i x[b,i] * ( sum_j Theta[i,j] * (l_j > l_i) * x[b,j] )
// B operand = Theta's OWN ROWS (k = j contiguous) — no transpose.
//
//  blocks [0, 1280): masked streaming bf16 convert (4 rows/block, 1 row/wave):
//      Tb[i][j] = bf16(theta[i*5120+j]) if j >= jmin_i else 0
//      jmin_i = 20*(i/20 + 1); stored for j >= js, js = 1024-chunk-aligned
//      start for i's 256-row GEMM n-tile (matches k_quad's c0 formula).
//  blocks [1280, 2304): per batch row b:
//      out[b] = theta_0 + dot(theta_lc, x[b]);  Xb[b,:] = bf16(x[b,:])
// ---------------------------------------------------------------------------
__global__ __launch_bounds__(256) void k_prep(
    const float* __restrict__ th,    // [5120,5120] theta_lclc
    const float* __restrict__ x,     // [1024,5120]
    const float* __restrict__ th0,   // [1]
    const float* __restrict__ thlc,  // [5120]
    unsigned short* __restrict__ Tb, // [5120,5120] bf16 masked theta (row-major)
    unsigned short* __restrict__ Xb, // [1024,5120] bf16 x
    float*          __restrict__ out)
{
    const int tid = threadIdx.x;
    if (blockIdx.x < LCN / 4) {
        // ---- masked streaming convert of theta rows ----
        const int w = tid >> 6, lane = tid & 63;
        const int i = blockIdx.x * 4 + w;                  // row (groups never straddle 256)
        const int lmin = ((i >> 8) << 8) / CN;             // min l in this row's 256-tile
        const int js   = 1024 * ((CN * (lmin + 1)) / 1024);// first chunk-aligned col stored
        const int jmin = CN * (i / CN) + CN;               // mask: valid iff j >= jmin
        const float* src = th + (size_t)i * LCN;
        unsigned short* dst = Tb + (size_t)i * LCN;
        // (5120 - js) is a multiple of 512 -> uniform trip count across lanes
        for (int j = js + lane * 8; j < LCN; j += 512) {
            const floatx4 v0 = *reinterpret_cast<const floatx4*>(src + j);
            const floatx4 v1 = *reinterpret_cast<const floatx4*>(src + j + 4);
            ushortx8 o;
#pragma unroll
            for (int e = 0; e < 4; ++e) o[e]     = (j + e     >= jmin) ? f2bf(v0[e]) : (unsigned short)0;
#pragma unroll
            for (int e = 0; e < 4; ++e) o[4 + e] = (j + 4 + e >= jmin) ? f2bf(v1[e]) : (unsigned short)0;
            *reinterpret_cast<ushortx8*>(dst + j) = o;
        }
    } else {
        // ---- linear term + x -> bf16 ----
        const int b = blockIdx.x - LCN / 4;
        const floatx4* xr = reinterpret_cast<const floatx4*>(x + (size_t)b * LCN);
        const floatx4* tr = reinterpret_cast<const floatx4*>(thlc);
        ushortx4* xw = reinterpret_cast<ushortx4*>(Xb + (size_t)b * LCN);
        float s = 0.0f;
        for (int k = tid; k < LCN / 4; k += 256) {
            const floatx4 a = xr[k], t2 = tr[k];
            s += a[0] * t2[0] + a[1] * t2[1] + a[2] * t2[2] + a[3] * t2[3];
            ushortx4 o;
#pragma unroll
            for (int e = 0; e < 4; ++e) o[e] = f2bf(a[e]);
            xw[k] = o;
        }
#pragma unroll
        for (int off = 32; off > 0; off >>= 1) s += __shfl_down(s, off, 64);
        __shared__ float ws4[4];
        if ((tid & 63) == 0) ws4[tid >> 6] = s;
        __syncthreads();
        if (tid == 0) out[b] = th0[0] + ws4[0] + ws4[1] + ws4[2] + ws4[3];
    }
}

// ---------------------------------------------------------------------------
// Pass 2: masked-GEMM + fused dot-reduce.  m201-style LOCKSTEP schedule.
// 256x256 tile, BK=32, 8 waves (2M x 4N), K-chunks of 1024 -> 32 K-tiles.
// 60 suffix chunks x 4 m-tiles = 240 blocks (grid 256, 16 early-exit);
// m-siblings of a chunk share an XCD (bid%8 RR) -> Tb HBM-fetched once.
//
// 4 LDS buffers (129 KB), stage lead = 3 TILES (counted vmcnt(8), never 0
// until the final 2-tile drain; tile-t loads issued ~3600 cyc before use).
// Each K-tile = 2 PHASES of 16 MFMA (m201 rhythm, 1 barrier per 8 K):
//   phase 0: read B frags (4) + A frags mt0-3 (4) -> issue 2 A-stage loads
//            -> s_barrier -> setprio(1) 16 MFMA setprio(0) -> s_barrier
//   phase 1: read A frags mt4-7 (4, B carried in regs) -> 2 B-stage loads
//            -> s_barrier -> setprio(1) 16 MFMA setprio(0)
//   (phase-1 post-barrier merges with the next tile-top barrier)
// LDS SEG SWIZZLE (0-conflict, measured): seg g of row r at slot (g+r)&3;
// writers use pre-permuted constant global seg; readers slot (kq+row)&3.
// ---------------------------------------------------------------------------
__global__ __launch_bounds__(512, 2) void k_quad(
    const unsigned short* __restrict__ Xb,   // [1024][5120] bf16
    const unsigned short* __restrict__ Tb,   // [5120][5120] bf16 masked theta
    float*                __restrict__ out)  // [1024]
{
    const int bid  = blockIdx.x;
    const int xcd  = bid & 7;
    const int slot = bid >> 3;
    const int m    = slot & 3;    // M tile (256 rows of batch)
    const int cl   = slot >> 2;   // chunk-local index on this XCD
    int qc = cl * 8 + xcd;        // chunk ordinal 0..59
    if (qc >= 60) return;

    // map chunk ordinal -> (n-tile, k-chunk) over 1024-wide suffix chunks
    int n = 0, cs = 0;
    for (int t = 0; t < 20; ++t) {
        const int lmin = (256 * t) / CN;
        const int c0   = (CN * (lmin + 1)) / 1024;
        const int cnt  = 5 - c0;
        if (qc < cnt) { n = t; cs = c0 + qc; break; }
        qc -= cnt;
    }
    const int b0 = m * 256;
    const int n0 = n * 256;
    const int k0 = cs * 1024;

    __shared__ unsigned short As[4 * 256 * 32];   // 4-buf A: [row][4 swizzled 16B segs]
    __shared__ unsigned short Bs[4 * 256 * 32];   // 4-buf B
    __shared__ float partial[256];

    const int tid  = threadIdx.x;
    const int lane = tid & 63;
    const int w    = tid >> 6;        // wave 0..7
    const int wm   = w & 1;           // M half (128 rows)
    const int wn   = w >> 1;          // N quarter (64 cols)
    const int lrow = lane & 15;
    const int kq   = lane >> 4;       // 0..3

    if (tid < 256) partial[tid] = 0.0f;

    floatx4 acc[8][4];
#pragma unroll
    for (int mt = 0; mt < 8; ++mt)
#pragma unroll
        for (int nt = 0; nt < 4; ++nt) acc[mt][nt] = (floatx4)0.0f;

    // ---- fragment read offsets (ushort units within one 8192-ush buffer) ----
    // frag (row, kq) lives at slot (kq + row) & 3 of its row.
    int aoff[8], boff[4];
#pragma unroll
    for (int mt = 0; mt < 8; ++mt) {
        const int row = wm * 128 + mt * 16 + lrow;
        aoff[mt] = row * 32 + (((kq + row) & 3) << 3);
    }
#pragma unroll
    for (int nt = 0; nt < 4; ++nt) {
        const int row = wn * 64 + nt * 16 + lrow;
        boff[nt] = row * 32 + (((kq + row) & 3) << 3);
    }

    // ---- staging constants (fixed per thread) ----
    // linear 16B-seg index S = round*512 + tid; row = S>>2; slot = S&3;
    // slot holds global seg ((S&3) - row) & 3 (constant per thread).
    const int srow = tid >> 2;                    // 0..127
    const int gseg = ((tid & 3) - (srow & 3)) & 3;
    const unsigned short* aS[2];
    const unsigned short* bS[2];
#pragma unroll
    for (int r = 0; r < 2; ++r) {
        aS[r] = Xb + (size_t)(b0 + r * 128 + srow) * LCN + k0 + gseg * 8;
        bS[r] = Tb + (size_t)(n0 + r * 128 + srow) * LCN + k0 + gseg * 8;
    }

#define STAGE_A(PAR) do {                                                         \
    _Pragma("unroll")                                                             \
    for (int r = 0; r < 2; ++r) {                                                 \
        char* la = (char*)As + (PAR) * 16384 + (size_t)(r * 512 + w * 64) * 16;   \
        gload_lds16(aS[r], la); aS[r] += 32;                                      \
    }                                                                             \
} while (0)

#define STAGE_B(PAR) do {                                                         \
    _Pragma("unroll")                                                             \
    for (int r = 0; r < 2; ++r) {                                                 \
        char* lb = (char*)Bs + (PAR) * 16384 + (size_t)(r * 512 + w * 64) * 16;   \
        gload_lds16(bS[r], lb); bS[r] += 32;                                      \
    }                                                                             \
} while (0)

    // one K-tile = 2 lockstep phases; VM = counted vmcnt literal at tile top
#define TILE(t_, PAR, VM) do {                                                     \
    asm volatile("s_waitcnt vmcnt(" #VM ")" ::: "memory");                         \
    __builtin_amdgcn_s_barrier();                                                  \
    const unsigned short* Ab = As + (PAR) * 8192;                                  \
    const unsigned short* Bb = Bs + (PAR) * 8192;                                  \
    shortx8 bfv[4], af[4];                                                         \
    _Pragma("unroll")                                                              \
    for (int nt = 0; nt < 4; ++nt)                                                 \
        bfv[nt] = *reinterpret_cast<const shortx8*>(Bb + boff[nt]);                \
    _Pragma("unroll")                                                              \
    for (int a = 0; a < 4; ++a)                                                    \
        af[a] = *reinterpret_cast<const shortx8*>(Ab + aoff[a]);                   \
    if ((t_) + 3 < 32) STAGE_A(((PAR) + 3) & 3);                                   \
    __builtin_amdgcn_s_barrier();                                                  \
    __builtin_amdgcn_s_setprio(1);                                                 \
    _Pragma("unroll")                                                              \
    for (int a = 0; a < 4; ++a)                                                    \
        _Pragma("unroll")                                                          \
        for (int nt = 0; nt < 4; ++nt)                                             \
            acc[a][nt] = __builtin_amdgcn_mfma_f32_16x16x32_bf16(af[a], bfv[nt], acc[a][nt], 0, 0, 0); \
    __builtin_amdgcn_s_setprio(0);                                                 \
    __builtin_amdgcn_s_barrier();                                                  \
    _Pragma("unroll")                                                              \
    for (int a = 0; a < 4; ++a)                                                    \
        af[a] = *reinterpret_cast<const shortx8*>(Ab + aoff[4 + a]);               \
    if ((t_) + 3 < 32) STAGE_B(((PAR) + 3) & 3);                                   \
    __builtin_amdgcn_s_barrier();                                                  \
    __builtin_amdgcn_s_setprio(1);                                                 \
    _Pragma("unroll")                                                              \
    for (int a = 0; a < 4; ++a)                                                    \
        _Pragma("unroll")                                                          \
        for (int nt = 0; nt < 4; ++nt)                                             \
            acc[4 + a][nt] = __builtin_amdgcn_mfma_f32_16x16x32_bf16(af[a], bfv[nt], acc[4 + a][nt], 0, 0, 0); \
    __builtin_amdgcn_s_setprio(0);                                                 \
} while (0)

    // prologue: tiles 0,1,2 staged (12 loads in flight)
    STAGE_A(0); STAGE_B(0);
    STAGE_A(1); STAGE_B(1);
    STAGE_A(2); STAGE_B(2);

    for (int t = 0; t < 28; t += 4) {
        TILE(t + 0, 0, 8);
        TILE(t + 1, 1, 8);
        TILE(t + 2, 2, 8);
        TILE(t + 3, 3, 8);
    }
    // tail: lead shrinks; counted waits drain 8 -> 8 -> 4 -> 0
    TILE(28, 0, 8);
    TILE(29, 1, 8);
    TILE(30, 2, 4);
    TILE(31, 3, 0);
#undef TILE
#undef STAGE_A
#undef STAGE_B

    // Epilogue: C/D layout col = lane&15 (i), row = (lane>>4)*4 + reg (b)
#pragma unroll
    for (int mt = 0; mt < 8; ++mt) {
#pragma unroll
        for (int r = 0; r < 4; ++r) {
            const int b = b0 + wm * 128 + mt * 16 + kq * 4 + r;
            float s = 0.0f;
#pragma unroll
            for (int nt = 0; nt < 4; ++nt) {
                const int i = n0 + wn * 64 + nt * 16 + lrow;
                const __hip_bfloat16 hv = *reinterpret_cast<const __hip_bfloat16*>(&Xb[(size_t)b * LCN + i]);
                s += acc[mt][nt][r] * __bfloat162float(hv);
            }
            s += __shfl_xor(s, 1, 64);
            s += __shfl_xor(s, 2, 64);
            s += __shfl_xor(s, 4, 64);
            s += __shfl_xor(s, 8, 64);
            if (lrow == 0) atomicAdd(&partial[b - b0], s);
        }
    }
    __syncthreads();
    if (tid < 256) atomicAdd(&out[b0 + tid], partial[tid]);
}

// ---------------------------------------------------------------------------
extern "C" void kernel_launch(void* const* d_in, const int* in_sizes, int n_in,
                              void* d_out, int out_size, void* d_ws, size_t ws_size,
                              hipStream_t stream) {
    const float* x      = (const float*)d_in[0];  // [1024, 5120]
    const float* th0    = (const float*)d_in[1];  // [1]
    const float* thlc   = (const float*)d_in[2];  // [5120]
    const float* thlclc = (const float*)d_in[3];  // [5120, 5120]
    float* out = (float*)d_out;                   // [1024]

    // ws layout: Tb (bf16 5120x5120 = 52.4 MB) | Xb (bf16 1024x5120 = 10.5 MB)
    unsigned short* Tb = (unsigned short*)d_ws;
    unsigned short* Xb = (unsigned short*)((char*)d_ws + (size_t)LCN * LCN * 2);

    // fused prep: 1280 theta-convert blocks + 1024 init blocks
    k_prep<<<dim3(LCN / 4 + BN), 256, 0, stream>>>(thlclc, x, th0, thlc, Tb, Xb, out);

    // 60 chunks x 4 m-tiles, padded to 8 chunk-slots per XCD: 8*8*4 = 256 blocks
    k_quad<<<dim3(256), 512, 0, stream>>>(Xb, Tb, out);
}